// Round 2
// baseline (421.429 us; speedup 1.0000x reference)
//
#include <hip/hip_runtime.h>
#include <hip/hip_bf16.h>

// MHA block: B=8, S=1024, H=1024, NH=16, DK=64
// d_in: 0=enc f32[8,1024,1024] 1=mask i32[8,1,1024,1024] 2..5=W_Q,K,V,O f32[1024,1024]
//       6=ln_gamma f32[1024] 7=ln_beta f32[1024]
// d_out: out f32[8,1024,1024] (8M) then attn f32[8,16,1024,1024] (128M)

typedef __bf16 bf16;
typedef __attribute__((ext_vector_type(8))) __bf16 bf16x8;
typedef __attribute__((ext_vector_type(4))) __bf16 bf16x4;
typedef __attribute__((ext_vector_type(4))) float f32x4;

#define MFMA16(a, b, c) __builtin_amdgcn_mfma_f32_16x16x32_bf16((a), (b), (c), 0, 0, 0)

#define B_ 8
#define S_ 1024
#define NH_ 16
#define DK_ 64
#define H_ 1024

__device__ __forceinline__ void gload_lds16(const void* g, void* l) {
  __builtin_amdgcn_global_load_lds(
      (__attribute__((address_space(1))) void*)g,
      (__attribute__((address_space(3))) void*)l, 16, 0, 0);
}

// ---------------- f32 -> bf16 convert (vectorized) ----------------
__global__ __launch_bounds__(256) void cvt_bf16_kern(const float* __restrict__ in,
                                                     bf16* __restrict__ out, int n4) {
  int i = blockIdx.x * 256 + threadIdx.x;
  if (i < n4) {
    float4 v = ((const float4*)in)[i];
    bf16x4 o;
    o[0] = (bf16)v.x; o[1] = (bf16)v.y; o[2] = (bf16)v.z; o[3] = (bf16)v.w;
    ((bf16x4*)out)[i] = o;
  }
}

// ---------------- mask i32 -> u8 convert ----------------
__global__ __launch_bounds__(256) void cvt_mask_kern(const int* __restrict__ in,
                                                     unsigned char* __restrict__ out, int n4) {
  int i = blockIdx.x * 256 + threadIdx.x;
  if (i < n4) {
    int4 v = ((const int4*)in)[i];
    uchar4 o;
    o.x = (unsigned char)v.x; o.y = (unsigned char)v.y;
    o.z = (unsigned char)v.z; o.w = (unsigned char)v.w;
    ((uchar4*)out)[i] = o;
  }
}

// ---------------- 128x128 tile bf16 GEMM, C = A * Bt^T ----------------
// A [M][K] bf16 row-major, Bt [N][K] bf16 row-major (i.e. B transposed).
// F32OUT: C f32 = acc + resid (ldc), else C bf16 = acc.
template <bool F32OUT>
__global__ __launch_bounds__(256) void gemm_bt_kern(const bf16* __restrict__ A,
                                                    const bf16* __restrict__ Bt,
                                                    void* __restrict__ Cout,
                                                    const float* __restrict__ resid,
                                                    int K, int ldc) {
  __shared__ bf16 As[128 * 32];  // 8KB
  __shared__ bf16 Bs[128 * 32];  // 8KB
  // XCD-aware bijective swizzle (grid counts are multiples of 8)
  const int lin = blockIdx.y * gridDim.x + blockIdx.x;
  const int nwg = gridDim.x * gridDim.y;
  const int chunk = nwg >> 3;
  const int v = (lin & 7) * chunk + (lin >> 3);
  const int m0 = (v / gridDim.x) * 128, n0 = (v % gridDim.x) * 128;
  const int tid = threadIdx.x;
  const int w = tid >> 6, l = tid & 63, l15 = l & 15, lg = l >> 4;
  const int wm = w >> 1, wn = w & 1;  // 2x2 waves of 64x64

  const bf16* Ab = A + (size_t)(m0 + (tid >> 2)) * K + (tid & 3) * 8;
  const bf16* Bb = Bt + (size_t)(n0 + (tid >> 2)) * K + (tid & 3) * 8;
  char* AsB = (char*)As + tid * 16;
  char* BsB = (char*)Bs + tid * 16;

  f32x4 acc[4][4] = {};
  for (int k0 = 0; k0 < K; k0 += 32) {
    gload_lds16(Ab + k0, AsB);                          // rows 0..63
    gload_lds16(Ab + (size_t)64 * K + k0, AsB + 4096);  // rows 64..127
    gload_lds16(Bb + k0, BsB);
    gload_lds16(Bb + (size_t)64 * K + k0, BsB + 4096);
    __syncthreads();
    bf16x8 af[4], bfv[4];
#pragma unroll
    for (int m = 0; m < 4; m++)
      af[m] = *(const bf16x8*)&As[(wm * 64 + m * 16 + l15) * 32 + lg * 8];
#pragma unroll
    for (int n = 0; n < 4; n++)
      bfv[n] = *(const bf16x8*)&Bs[(wn * 64 + n * 16 + l15) * 32 + lg * 8];
#pragma unroll
    for (int m = 0; m < 4; m++)
#pragma unroll
      for (int n = 0; n < 4; n++) acc[m][n] = MFMA16(af[m], bfv[n], acc[m][n]);
    __syncthreads();
  }
#pragma unroll
  for (int m = 0; m < 4; m++)
#pragma unroll
    for (int n = 0; n < 4; n++)
#pragma unroll
      for (int j = 0; j < 4; j++) {
        int row = m0 + wm * 64 + m * 16 + lg * 4 + j;
        int col = n0 + wn * 64 + n * 16 + l15;
        if constexpr (F32OUT) {
          ((float*)Cout)[(size_t)row * ldc + col] =
              acc[m][n][j] + resid[(size_t)row * ldc + col];
        } else {
          ((bf16*)Cout)[(size_t)row * ldc + col] = (bf16)acc[m][n][j];
        }
      }
}

// ---------------- V transpose: qkv V-part -> vT[(b*NH+h)*DK + d][S] ----------------
__global__ __launch_bounds__(256) void vtrans_kern(const bf16* __restrict__ qkv,
                                                   bf16* __restrict__ vT) {
  int blk = blockIdx.x;
  int st = blk & 15;          // seq tile of 64
  int h = (blk >> 4) & 15;
  int b = blk >> 8;
  __shared__ bf16 t[64][65];
  int tid = threadIdx.x;
  {
    int r = tid >> 2, cb = (tid & 3) * 16;
    const bf16* src = qkv + ((size_t)(b * S_ + st * 64 + r)) * 3072 + 2048 + h * DK_ + cb;
    bf16x8 u0 = *(const bf16x8*)src;
    bf16x8 u1 = *(const bf16x8*)(src + 8);
#pragma unroll
    for (int j = 0; j < 8; j++) { t[r][cb + j] = u0[j]; t[r][cb + 8 + j] = u1[j]; }
  }
  __syncthreads();
  {
    int d = tid >> 2, sb = (tid & 3) * 16;
    bf16* dst = vT + ((size_t)((b * NH_ + h) * DK_ + d)) * S_ + st * 64 + sb;
#pragma unroll
    for (int j = 0; j < 16; j++) dst[j] = t[sb + j][d];
  }
}

// ---------------- fused attention: scores -> mask -> softmax -> attn out + PV ----------------
// grid: B*NH*(S/32)=4096 blocks, 256 threads (4 waves). Wave w owns score cols [w*256,+256).
// XCD swizzle: each XCD gets one contiguous chunk of 512 vblks = exactly one batch b;
// within chunk, qt fastest (adjacent blocks share K/V panels -> L2-hot), mask per-b (1MB u8)
// fits the 4MB per-XCD L2.
__global__ __launch_bounds__(256, 2) void attn_kern(const bf16* __restrict__ qkv,
                                                    const bf16* __restrict__ vT,
                                                    const unsigned char* __restrict__ mask8,
                                                    float* __restrict__ attn_out,
                                                    bf16* __restrict__ ctx) {
  __shared__ bf16 p_lds[32 * 1024];  // 64KB; first 1KB aliased as cross-wave reduce buf
  float(*red)[32][2] = (float(*)[32][2])p_lds;

  const int vb = (blockIdx.x & 7) * 512 + (blockIdx.x >> 3);
  const int qt = vb & 31;
  const int h = (vb >> 5) & 15;
  const int b = vb >> 9;
  const int q0 = qt * 32;
  const int tid = threadIdx.x;
  const int w = tid >> 6, l = tid & 63, l15 = l & 15, lg = l >> 4;

  // Q fragments (A operand), rows q0..q0+31, k = DK 0..63
  const bf16* qbase = qkv + ((size_t)(b * S_ + q0)) * 3072 + h * DK_;
  bf16x8 aq[2][2];
#pragma unroll
  for (int m = 0; m < 2; m++)
#pragma unroll
    for (int kk = 0; kk < 2; kk++)
      aq[m][kk] = *(const bf16x8*)(qbase + (size_t)(m * 16 + l15) * 3072 + kk * 32 + lg * 8);

  // scores: sc[nb][m][n] covers rows 0..31 x cols w*256+nb*64 .. +63
  f32x4 sc[4][2][4] = {};
  const bf16* kbase = qkv + ((size_t)(b * S_)) * 3072 + 1024 + h * DK_;
#pragma unroll
  for (int nb = 0; nb < 4; nb++) {
    int n0 = w * 256 + nb * 64;
#pragma unroll
    for (int n = 0; n < 4; n++)
#pragma unroll
      for (int kk = 0; kk < 2; kk++) {
        bf16x8 bk = *(const bf16x8*)(kbase + (size_t)(n0 + n * 16 + l15) * 3072 + kk * 32 + lg * 8);
#pragma unroll
        for (int m = 0; m < 2; m++) sc[nb][m][n] = MFMA16(aq[m][kk], bk, sc[nb][m][n]);
      }
  }

  // scale + mask; per-lane row max (lane holds rows m*16+lg*4+j, 16 vals each)
  const unsigned char* mbase = mask8 + (size_t)b * S_ * S_;
  float rmax[2][4], rsum[2][4];
#pragma unroll
  for (int m = 0; m < 2; m++)
#pragma unroll
    for (int j = 0; j < 4; j++) rmax[m][j] = -3e38f;
#pragma unroll
  for (int nb = 0; nb < 4; nb++)
#pragma unroll
    for (int n = 0; n < 4; n++)
#pragma unroll
      for (int m = 0; m < 2; m++)
#pragma unroll
        for (int j = 0; j < 4; j++) {
          int r = m * 16 + lg * 4 + j;
          int c = w * 256 + nb * 64 + n * 16 + l15;
          float s = sc[nb][m][n][j] * 0.125f;  // 1/sqrt(DK)
          if (mbase[(size_t)(q0 + r) * S_ + c] == 0) s = -1e9f;
          sc[nb][m][n][j] = s;
          rmax[m][j] = fmaxf(rmax[m][j], s);
        }
  // reduce max across the 16 lanes sharing each row
#pragma unroll
  for (int m = 0; m < 2; m++)
#pragma unroll
    for (int j = 0; j < 4; j++) {
      float v = rmax[m][j];
#pragma unroll
      for (int mm = 1; mm < 16; mm <<= 1) v = fmaxf(v, __shfl_xor(v, mm));
      rmax[m][j] = v;
    }
  // e = exp(s - wave_max) stored back into sc; per-row wave sums
#pragma unroll
  for (int m = 0; m < 2; m++)
#pragma unroll
    for (int j = 0; j < 4; j++) rsum[m][j] = 0.f;
#pragma unroll
  for (int nb = 0; nb < 4; nb++)
#pragma unroll
    for (int n = 0; n < 4; n++)
#pragma unroll
      for (int m = 0; m < 2; m++)
#pragma unroll
        for (int j = 0; j < 4; j++) {
          float e = __expf(sc[nb][m][n][j] - rmax[m][j]);
          sc[nb][m][n][j] = e;
          rsum[m][j] += e;
        }
#pragma unroll
  for (int m = 0; m < 2; m++)
#pragma unroll
    for (int j = 0; j < 4; j++) {
      float v = rsum[m][j];
#pragma unroll
      for (int mm = 1; mm < 16; mm <<= 1) v += __shfl_xor(v, mm);
      rsum[m][j] = v;
    }
  if (l15 == 0) {
#pragma unroll
    for (int m = 0; m < 2; m++)
#pragma unroll
      for (int j = 0; j < 4; j++) {
        int r = m * 16 + lg * 4 + j;
        red[w][r][0] = rmax[m][j];
        red[w][r][1] = rsum[m][j];
      }
  }
  __syncthreads();
  // combine across 4 waves -> per-row scale = exp(rmax_w - gmax)/gsum
  float scale[2][4];
#pragma unroll
  for (int m = 0; m < 2; m++)
#pragma unroll
    for (int j = 0; j < 4; j++) {
      int r = m * 16 + lg * 4 + j;
      float m0v = red[0][r][0], m1 = red[1][r][0], m2 = red[2][r][0], m3 = red[3][r][0];
      float gm = fmaxf(fmaxf(m0v, m1), fmaxf(m2, m3));
      float gs = red[0][r][1] * __expf(m0v - gm) + red[1][r][1] * __expf(m1 - gm) +
                 red[2][r][1] * __expf(m2 - gm) + red[3][r][1] * __expf(m3 - gm);
      scale[m][j] = __expf(rmax[m][j] - gm) / gs;
    }
  __syncthreads();  // red reads done before p_lds writes (aliased)

  // write attn f32 (output) + swizzled bf16 P into LDS
  float* arow = attn_out + ((size_t)(b * NH_ + h) * S_ + q0) * S_;
#pragma unroll
  for (int nb = 0; nb < 4; nb++)
#pragma unroll
    for (int n = 0; n < 4; n++)
#pragma unroll
      for (int m = 0; m < 2; m++)
#pragma unroll
        for (int j = 0; j < 4; j++) {
          int r = m * 16 + lg * 4 + j;
          int c = w * 256 + nb * 64 + n * 16 + l15;
          float p = sc[nb][m][n][j] * scale[m][j];
          arow[(size_t)r * S_ + c] = p;
          p_lds[r * 1024 + (c ^ ((r & 7) << 3))] = (bf16)p;  // XOR swizzle vs 16-way conflict
        }
  __syncthreads();

  // PV: wave w computes out[:, w*16 .. w*16+15]; B^T rows are vT rows (contiguous k)
  f32x4 o[2] = {};
  const bf16* vbase = vT + ((size_t)((b * NH_ + h) * DK_ + w * 16 + l15)) * S_;
#pragma unroll 8
  for (int ks = 0; ks < 32; ks++) {
    bf16x8 bv = *(const bf16x8*)(vbase + ks * 32 + lg * 8);
#pragma unroll
    for (int m = 0; m < 2; m++) {
      int r = m * 16 + l15;
      int e = (ks * 32 + lg * 8) ^ ((r & 7) << 3);
      bf16x8 pa = *(const bf16x8*)&p_lds[r * 1024 + e];
      o[m] = MFMA16(pa, bv, o[m]);
    }
  }
#pragma unroll
  for (int m = 0; m < 2; m++)
#pragma unroll
    for (int j = 0; j < 4; j++) {
      int r = m * 16 + lg * 4 + j;
      ctx[((size_t)(b * S_ + q0 + r)) * H_ + h * DK_ + w * 16 + l15] = (bf16)o[m][j];
    }
}

// ---------------- in-place LayerNorm over last dim (1024) ----------------
__global__ __launch_bounds__(256) void ln_kern(float* __restrict__ y,
                                               const float* __restrict__ gamma,
                                               const float* __restrict__ beta) {
  int row = blockIdx.x;
  int tid = threadIdx.x;
  float4 v = *(const float4*)&y[(size_t)row * 1024 + tid * 4];
  float s = v.x + v.y + v.z + v.w;
  float q = v.x * v.x + v.y * v.y + v.z * v.z + v.w * v.w;
#pragma unroll
  for (int m = 1; m < 64; m <<= 1) { s += __shfl_xor(s, m); q += __shfl_xor(q, m); }
  __shared__ float rb[8];
  if ((tid & 63) == 0) { rb[(tid >> 6) * 2] = s; rb[(tid >> 6) * 2 + 1] = q; }
  __syncthreads();
  s = rb[0] + rb[2] + rb[4] + rb[6];
  q = rb[1] + rb[3] + rb[5] + rb[7];
  float mu = s * (1.f / 1024.f);
  float var = q * (1.f / 1024.f) - mu * mu;
  float rstd = rsqrtf(var + 1e-6f);
  float4 g = *(const float4*)&gamma[tid * 4];
  float4 bb = *(const float4*)&beta[tid * 4];
  float4 o;
  o.x = (v.x - mu) * rstd * g.x + bb.x;
  o.y = (v.y - mu) * rstd * g.y + bb.y;
  o.z = (v.z - mu) * rstd * g.z + bb.z;
  o.w = (v.w - mu) * rstd * g.w + bb.w;
  *(float4*)&y[(size_t)row * 1024 + tid * 4] = o;
}

extern "C" void kernel_launch(void* const* d_in, const int* in_sizes, int n_in,
                              void* d_out, int out_size, void* d_ws, size_t ws_size,
                              hipStream_t stream) {
  const float* enc = (const float*)d_in[0];
  const int* mask = (const int*)d_in[1];
  const float* W_Q = (const float*)d_in[2];
  const float* W_K = (const float*)d_in[3];
  const float* W_V = (const float*)d_in[4];
  const float* W_O = (const float*)d_in[5];
  const float* ln_g = (const float*)d_in[6];
  const float* ln_b = (const float*)d_in[7];

  float* out_f32 = (float*)d_out;                          // [8192][1024]
  float* attn_f32 = (float*)d_out + (size_t)B_ * S_ * H_;  // [128][1024][1024]

  // ws layout (bytes): enc_bf 16M (later aliased by mask8 8M) | wqkv_bf 6M | wo_bf 2M |
  //                    qkv 48M | vT 16M | ctx 16M  (~104MB)
  char* wsb = (char*)d_ws;
  bf16* enc_bf = (bf16*)wsb;
  unsigned char* mask8 = (unsigned char*)wsb;  // aliases enc_bf AFTER QKV gemm
  bf16* wqkv = (bf16*)(wsb + 16777216);
  bf16* wo = (bf16*)(wsb + 23068672);
  bf16* qkv = (bf16*)(wsb + 25165824);
  bf16* vT = (bf16*)(wsb + 75497472);
  bf16* ctx = (bf16*)(wsb + 92274688);

  // 1) converts
  cvt_bf16_kern<<<8192, 256, 0, stream>>>(enc, enc_bf, 2097152);
  cvt_bf16_kern<<<1024, 256, 0, stream>>>(W_Q, wqkv, 262144);
  cvt_bf16_kern<<<1024, 256, 0, stream>>>(W_K, wqkv + 1048576, 262144);
  cvt_bf16_kern<<<1024, 256, 0, stream>>>(W_V, wqkv + 2097152, 262144);
  cvt_bf16_kern<<<1024, 256, 0, stream>>>(W_O, wo, 262144);

  // 2) QKV projection: [8192,1024] x [3072,1024]^T -> qkv bf16 [8192][3072]
  gemm_bt_kern<false><<<dim3(24, 64), 256, 0, stream>>>(enc_bf, wqkv, qkv, nullptr, 1024, 3072);

  // 3) V transpose -> vT[(b*16+h)*64 + d][1024];  mask -> u8 (enc_bf now dead)
  vtrans_kern<<<2048, 256, 0, stream>>>(qkv, vT);
  cvt_mask_kern<<<8192, 256, 0, stream>>>(mask, mask8, 2097152);

  // 4) fused attention (+ writes attn_dist output)
  attn_kern<<<4096, 256, 0, stream>>>(qkv, vT, mask8, attn_f32, ctx);

  // 5) output projection + residual -> d_out (pre-LN f32)
  gemm_bt_kern<true><<<dim3(8, 64), 256, 0, stream>>>(ctx, wo, out_f32, enc, 1024, 1024);

  // 6) in-place LayerNorm
  ln_kern<<<8192, 256, 0, stream>>>(out_f32, ln_g, ln_b);
}

// Round 4
// 414.676 us; speedup vs baseline: 1.0163x; 1.0163x over previous
//
#include <hip/hip_runtime.h>
#include <hip/hip_bf16.h>

// MHA block: B=8, S=1024, H=1024, NH=16, DK=64
// d_out: out f32[8,1024,1024] (8M) then attn f32[8,16,1024,1024] (128M)

typedef __bf16 bf16;
typedef __attribute__((ext_vector_type(8))) __bf16 bf16x8;
typedef __attribute__((ext_vector_type(4))) __bf16 bf16x4;
typedef __attribute__((ext_vector_type(4))) float f32x4;

#define MFMA16(a, b, c) __builtin_amdgcn_mfma_f32_16x16x32_bf16((a), (b), (c), 0, 0, 0)

#define B_ 8
#define S_ 1024
#define NH_ 16
#define DK_ 64
#define H_ 1024

__device__ __forceinline__ void gload_lds16(const void* g, void* l) {
  __builtin_amdgcn_global_load_lds(
      (__attribute__((address_space(1))) void*)g,
      (__attribute__((address_space(3))) void*)l, 16, 0, 0);
}

// ---------------- f32 -> bf16 convert (vectorized) ----------------
__global__ __launch_bounds__(256) void cvt_bf16_kern(const float* __restrict__ in,
                                                     bf16* __restrict__ out, int n4) {
  int i = blockIdx.x * 256 + threadIdx.x;
  if (i < n4) {
    float4 v = ((const float4*)in)[i];
    bf16x4 o;
    o[0] = (bf16)v.x; o[1] = (bf16)v.y; o[2] = (bf16)v.z; o[3] = (bf16)v.w;
    ((bf16x4*)out)[i] = o;
  }
}

// ---------------- mask i32 -> u8 convert ----------------
__global__ __launch_bounds__(256) void cvt_mask_kern(const int* __restrict__ in,
                                                     unsigned char* __restrict__ out, int n4) {
  int i = blockIdx.x * 256 + threadIdx.x;
  if (i < n4) {
    int4 v = ((const int4*)in)[i];
    uchar4 o;
    o.x = (unsigned char)v.x; o.y = (unsigned char)v.y;
    o.z = (unsigned char)v.z; o.w = (unsigned char)v.w;
    ((uchar4*)out)[i] = o;
  }
}

// ---------------- 128x128 tile bf16 GEMM, C = A * Bt^T ----------------
template <bool F32OUT>
__global__ __launch_bounds__(256) void gemm_bt_kern(const bf16* __restrict__ A,
                                                    const bf16* __restrict__ Bt,
                                                    void* __restrict__ Cout,
                                                    const float* __restrict__ resid,
                                                    int K, int ldc) {
  __shared__ bf16 As[128 * 32];  // 8KB
  __shared__ bf16 Bs[128 * 32];  // 8KB
  const int lin = blockIdx.y * gridDim.x + blockIdx.x;
  const int nwg = gridDim.x * gridDim.y;
  const int chunk = nwg >> 3;
  const int v = (lin & 7) * chunk + (lin >> 3);
  const int m0 = (v / gridDim.x) * 128, n0 = (v % gridDim.x) * 128;
  const int tid = threadIdx.x;
  const int w = tid >> 6, l = tid & 63, l15 = l & 15, lg = l >> 4;
  const int wm = w >> 1, wn = w & 1;  // 2x2 waves of 64x64

  const bf16* Ab = A + (size_t)(m0 + (tid >> 2)) * K + (tid & 3) * 8;
  const bf16* Bb = Bt + (size_t)(n0 + (tid >> 2)) * K + (tid & 3) * 8;
  char* AsB = (char*)As + tid * 16;
  char* BsB = (char*)Bs + tid * 16;

  f32x4 acc[4][4] = {};
  for (int k0 = 0; k0 < K; k0 += 32) {
    gload_lds16(Ab + k0, AsB);
    gload_lds16(Ab + (size_t)64 * K + k0, AsB + 4096);
    gload_lds16(Bb + k0, BsB);
    gload_lds16(Bb + (size_t)64 * K + k0, BsB + 4096);
    __syncthreads();
    bf16x8 af[4], bfv[4];
#pragma unroll
    for (int m = 0; m < 4; m++)
      af[m] = *(const bf16x8*)&As[(wm * 64 + m * 16 + l15) * 32 + lg * 8];
#pragma unroll
    for (int n = 0; n < 4; n++)
      bfv[n] = *(const bf16x8*)&Bs[(wn * 64 + n * 16 + l15) * 32 + lg * 8];
#pragma unroll
    for (int m = 0; m < 4; m++)
#pragma unroll
      for (int n = 0; n < 4; n++) acc[m][n] = MFMA16(af[m], bfv[n], acc[m][n]);
    __syncthreads();
  }
#pragma unroll
  for (int m = 0; m < 4; m++)
#pragma unroll
    for (int n = 0; n < 4; n++)
#pragma unroll
      for (int j = 0; j < 4; j++) {
        int row = m0 + wm * 64 + m * 16 + lg * 4 + j;
        int col = n0 + wn * 64 + n * 16 + l15;
        if constexpr (F32OUT) {
          ((float*)Cout)[(size_t)row * ldc + col] =
              acc[m][n][j] + resid[(size_t)row * ldc + col];
        } else {
          ((bf16*)Cout)[(size_t)row * ldc + col] = (bf16)acc[m][n][j];
        }
      }
}

// ---------------- V transpose: qkv V-part -> vT[(b*NH+h)*DK + d][S] ----------------
__global__ __launch_bounds__(256) void vtrans_kern(const bf16* __restrict__ qkv,
                                                   bf16* __restrict__ vT) {
  int blk = blockIdx.x;
  int st = blk & 15;
  int h = (blk >> 4) & 15;
  int b = blk >> 8;
  __shared__ bf16 t[64][65];
  int tid = threadIdx.x;
  {
    int r = tid >> 2, cb = (tid & 3) * 16;
    const bf16* src = qkv + ((size_t)(b * S_ + st * 64 + r)) * 3072 + 2048 + h * DK_ + cb;
    bf16x8 u0 = *(const bf16x8*)src;
    bf16x8 u1 = *(const bf16x8*)(src + 8);
#pragma unroll
    for (int j = 0; j < 8; j++) { t[r][cb + j] = u0[j]; t[r][cb + 8 + j] = u1[j]; }
  }
  __syncthreads();
  {
    int d = tid >> 2, sb = (tid & 3) * 16;
    bf16* dst = vT + ((size_t)((b * NH_ + h) * DK_ + d)) * S_ + st * 64 + sb;
#pragma unroll
    for (int j = 0; j < 16; j++) dst[j] = t[sb + j][d];
  }
}

// ---------------- fused attention (swapped QK^T: lane owns 4 consecutive keys) ----------------
// grid 4096, 256 thr (4 waves). Wave w owns keys [w*256, w*256+256).
// D' = K*Q^T: col = query = l15 (+m*16), row = key = lg*4+j (+n*16+nb*64+w*256).
__global__ __launch_bounds__(256, 2) void attn_kern(const bf16* __restrict__ qkv,
                                                    const bf16* __restrict__ vT,
                                                    const unsigned char* __restrict__ mask8,
                                                    float* __restrict__ attn_out,
                                                    bf16* __restrict__ ctx) {
  __shared__ bf16 p_lds[32 * 1024];  // 64KB; head aliased as cross-wave reduce buf
  float(*red)[32][2] = (float(*)[32][2])p_lds;

  const int vb = (blockIdx.x & 7) * 512 + (blockIdx.x >> 3);
  const int qt = vb & 31;
  const int h = (vb >> 5) & 15;
  const int b = vb >> 9;
  const int q0 = qt * 32;
  const int tid = threadIdx.x;
  const int w = tid >> 6, l = tid & 63, l15 = l & 15, lg = l >> 4;

  // Q fragments (B operand): lane holds Q[q=l15(+m*16)][dk=kk*32+lg*8+e]
  const bf16* qbase = qkv + ((size_t)(b * S_ + q0)) * 3072 + h * DK_;
  bf16x8 aq[2][2];
#pragma unroll
  for (int m = 0; m < 2; m++)
#pragma unroll
    for (int kk = 0; kk < 2; kk++)
      aq[m][kk] = *(const bf16x8*)(qbase + (size_t)(m * 16 + l15) * 3072 + kk * 32 + lg * 8);

  // scores: sc[nb][m][n][j] = S[key = w*256+nb*64+n*16+lg*4+j][query = m*16+l15]
  f32x4 sc[4][2][4] = {};
  const bf16* kbase = qkv + ((size_t)(b * S_)) * 3072 + 1024 + h * DK_;
#pragma unroll
  for (int nb = 0; nb < 4; nb++) {
    int n0 = w * 256 + nb * 64;
#pragma unroll
    for (int n = 0; n < 4; n++)
#pragma unroll
      for (int kk = 0; kk < 2; kk++) {
        bf16x8 bk = *(const bf16x8*)(kbase + (size_t)(n0 + n * 16 + l15) * 3072 + kk * 32 + lg * 8);
#pragma unroll
        for (int m = 0; m < 2; m++) sc[nb][m][n] = MFMA16(bk, aq[m][kk], sc[nb][m][n]);
      }
  }

  // scale (log2 domain) + mask via uchar4; per-lane in-register row reduce
  const unsigned char* mbase = mask8 + (size_t)b * S_ * S_;
  const float SCL = 0.125f * 1.44269504f;  // (1/sqrt(DK)) * log2(e)
  float rmax[2] = {-3e38f, -3e38f};
#pragma unroll
  for (int m = 0; m < 2; m++) {
    int q = q0 + m * 16 + l15;
#pragma unroll
    for (int nb = 0; nb < 4; nb++)
#pragma unroll
      for (int n = 0; n < 4; n++) {
        int kb = w * 256 + nb * 64 + n * 16 + lg * 4;
        uchar4 mv = *(const uchar4*)&mbase[(size_t)q * S_ + kb];
        unsigned char mb[4] = {mv.x, mv.y, mv.z, mv.w};
#pragma unroll
        for (int j = 0; j < 4; j++) {
          float s = sc[nb][m][n][j] * SCL;
          if (mb[j] == 0) s = -1e9f;
          sc[nb][m][n][j] = s;
          rmax[m] = fmaxf(rmax[m], s);
        }
      }
  }
  // reduce across lg lane groups (lanes sharing a query differ only in bits 4,5)
#pragma unroll
  for (int m = 0; m < 2; m++) {
    float v = rmax[m];
    v = fmaxf(v, __shfl_xor(v, 16));
    v = fmaxf(v, __shfl_xor(v, 32));
    rmax[m] = v;
  }
  float rsum[2] = {0.f, 0.f};
#pragma unroll
  for (int nb = 0; nb < 4; nb++)
#pragma unroll
    for (int n = 0; n < 4; n++)
#pragma unroll
      for (int m = 0; m < 2; m++)
#pragma unroll
        for (int j = 0; j < 4; j++) {
          float e = exp2f(sc[nb][m][n][j] - rmax[m]);
          sc[nb][m][n][j] = e;
          rsum[m] += e;
        }
#pragma unroll
  for (int m = 0; m < 2; m++) {
    float v = rsum[m];
    v += __shfl_xor(v, 16);
    v += __shfl_xor(v, 32);
    rsum[m] = v;
  }
  if (lg == 0) {
#pragma unroll
    for (int m = 0; m < 2; m++) {
      red[w][m * 16 + l15][0] = rmax[m];
      red[w][m * 16 + l15][1] = rsum[m];
    }
  }
  __syncthreads();
  float scale[2];
#pragma unroll
  for (int m = 0; m < 2; m++) {
    int q = m * 16 + l15;
    float m0v = red[0][q][0], m1 = red[1][q][0], m2 = red[2][q][0], m3 = red[3][q][0];
    float gm = fmaxf(fmaxf(m0v, m1), fmaxf(m2, m3));
    float gs = red[0][q][1] * exp2f(m0v - gm) + red[1][q][1] * exp2f(m1 - gm) +
               red[2][q][1] * exp2f(m2 - gm) + red[3][q][1] * exp2f(m3 - gm);
    scale[m] = exp2f(rmax[m] - gm) / gs;
  }
  __syncthreads();  // red reads done before p_lds writes (aliased)

  // write attn f32 (nontemporal f32x4) + swizzled bf16x4 P into LDS
  float* arow = attn_out + ((size_t)(b * NH_ + h) * S_ + q0) * S_;
#pragma unroll
  for (int m = 0; m < 2; m++) {
    int q = m * 16 + l15;
#pragma unroll
    for (int nb = 0; nb < 4; nb++)
#pragma unroll
      for (int n = 0; n < 4; n++) {
        int kb = w * 256 + nb * 64 + n * 16 + lg * 4;
        f32x4 p4;
        bf16x4 pb;
#pragma unroll
        for (int j = 0; j < 4; j++) {
          float p = sc[nb][m][n][j] * scale[m];
          p4[j] = p;
          pb[j] = (bf16)p;
        }
        __builtin_nontemporal_store(p4, (f32x4*)&arow[(size_t)q * S_ + kb]);
        *(bf16x4*)&p_lds[q * 1024 + (kb ^ ((q & 7) << 3))] = pb;
      }
  }
  __syncthreads();

  // PV: wave w computes out[:, w*16 .. w*16+15]
  f32x4 o[2] = {};
  const bf16* vbase = vT + ((size_t)((b * NH_ + h) * DK_ + w * 16 + l15)) * S_;
#pragma unroll 8
  for (int ks = 0; ks < 32; ks++) {
    bf16x8 bv = *(const bf16x8*)(vbase + ks * 32 + lg * 8);
#pragma unroll
    for (int m = 0; m < 2; m++) {
      int r = m * 16 + l15;
      int e = (ks * 32 + lg * 8) ^ ((r & 7) << 3);
      bf16x8 pa = *(const bf16x8*)&p_lds[r * 1024 + e];
      o[m] = MFMA16(pa, bv, o[m]);
    }
  }
#pragma unroll
  for (int m = 0; m < 2; m++)
#pragma unroll
    for (int j = 0; j < 4; j++) {
      int r = m * 16 + lg * 4 + j;
      ctx[((size_t)(b * S_ + q0 + r)) * H_ + h * DK_ + w * 16 + l15] = (bf16)o[m][j];
    }
}

// ---------------- in-place LayerNorm over last dim (1024) ----------------
__global__ __launch_bounds__(256) void ln_kern(float* __restrict__ y,
                                               const float* __restrict__ gamma,
                                               const float* __restrict__ beta) {
  int row = blockIdx.x;
  int tid = threadIdx.x;
  float4 v = *(const float4*)&y[(size_t)row * 1024 + tid * 4];
  float s = v.x + v.y + v.z + v.w;
  float q = v.x * v.x + v.y * v.y + v.z * v.z + v.w * v.w;
#pragma unroll
  for (int m = 1; m < 64; m <<= 1) { s += __shfl_xor(s, m); q += __shfl_xor(q, m); }
  __shared__ float rb[8];
  if ((tid & 63) == 0) { rb[(tid >> 6) * 2] = s; rb[(tid >> 6) * 2 + 1] = q; }
  __syncthreads();
  s = rb[0] + rb[2] + rb[4] + rb[6];
  q = rb[1] + rb[3] + rb[5] + rb[7];
  float mu = s * (1.f / 1024.f);
  float var = q * (1.f / 1024.f) - mu * mu;
  float rstd = rsqrtf(var + 1e-6f);
  float4 g = *(const float4*)&gamma[tid * 4];
  float4 bb = *(const float4*)&beta[tid * 4];
  float4 o;
  o.x = (v.x - mu) * rstd * g.x + bb.x;
  o.y = (v.y - mu) * rstd * g.y + bb.y;
  o.z = (v.z - mu) * rstd * g.z + bb.z;
  o.w = (v.w - mu) * rstd * g.w + bb.w;
  *(float4*)&y[(size_t)row * 1024 + tid * 4] = o;
}

extern "C" void kernel_launch(void* const* d_in, const int* in_sizes, int n_in,
                              void* d_out, int out_size, void* d_ws, size_t ws_size,
                              hipStream_t stream) {
  const float* enc = (const float*)d_in[0];
  const int* mask = (const int*)d_in[1];
  const float* W_Q = (const float*)d_in[2];
  const float* W_K = (const float*)d_in[3];
  const float* W_V = (const float*)d_in[4];
  const float* W_O = (const float*)d_in[5];
  const float* ln_g = (const float*)d_in[6];
  const float* ln_b = (const float*)d_in[7];

  float* out_f32 = (float*)d_out;                          // [8192][1024]
  float* attn_f32 = (float*)d_out + (size_t)B_ * S_ * H_;  // [128][1024][1024]

  char* wsb = (char*)d_ws;
  bf16* enc_bf = (bf16*)wsb;
  unsigned char* mask8 = (unsigned char*)wsb;  // aliases enc_bf AFTER QKV gemm
  bf16* wqkv = (bf16*)(wsb + 16777216);
  bf16* wo = (bf16*)(wsb + 23068672);
  bf16* qkv = (bf16*)(wsb + 25165824);
  bf16* vT = (bf16*)(wsb + 75497472);
  bf16* ctx = (bf16*)(wsb + 92274688);

  // 1) converts
  cvt_bf16_kern<<<8192, 256, 0, stream>>>(enc, enc_bf, 2097152);
  cvt_bf16_kern<<<1024, 256, 0, stream>>>(W_Q, wqkv, 262144);
  cvt_bf16_kern<<<1024, 256, 0, stream>>>(W_K, wqkv + 1048576, 262144);
  cvt_bf16_kern<<<1024, 256, 0, stream>>>(W_V, wqkv + 2097152, 262144);
  cvt_bf16_kern<<<1024, 256, 0, stream>>>(W_O, wo, 262144);

  // 2) QKV projection: [8192,1024] x [3072,1024]^T -> qkv bf16 [8192][3072]
  gemm_bt_kern<false><<<dim3(24, 64), 256, 0, stream>>>(enc_bf, wqkv, qkv, nullptr, 1024, 3072);

  // 3) V transpose; mask -> u8 (enc_bf now dead)
  vtrans_kern<<<2048, 256, 0, stream>>>(qkv, vT);
  cvt_mask_kern<<<8192, 256, 0, stream>>>(mask, mask8, 2097152);

  // 4) fused attention (+ writes attn_dist output)
  attn_kern<<<4096, 256, 0, stream>>>(qkv, vT, mask8, attn_f32, ctx);

  // 5) output projection + residual -> d_out (pre-LN f32)
  gemm_bt_kern<true><<<dim3(8, 64), 256, 0, stream>>>(ctx, wo, out_f32, enc, 1024, 1024);

  // 6) in-place LayerNorm
  ln_kern<<<8192, 256, 0, stream>>>(out_f32, ln_g, ln_b);
}

// Round 5
// 406.381 us; speedup vs baseline: 1.0370x; 1.0204x over previous
//
#include <hip/hip_runtime.h>
#include <hip/hip_bf16.h>

// MHA block: B=8, S=1024, H=1024, NH=16, DK=64
// d_out: out f32[8,1024,1024] (8M) then attn f32[8,16,1024,1024] (128M)

typedef __bf16 bf16;
typedef __attribute__((ext_vector_type(8))) __bf16 bf16x8;
typedef __attribute__((ext_vector_type(4))) __bf16 bf16x4;
typedef __attribute__((ext_vector_type(4))) float f32x4;

#define MFMA16(a, b, c) __builtin_amdgcn_mfma_f32_16x16x32_bf16((a), (b), (c), 0, 0, 0)

#define B_ 8
#define S_ 1024
#define NH_ 16
#define DK_ 64
#define H_ 1024

__device__ __forceinline__ void gload_lds16(const void* g, void* l) {
  __builtin_amdgcn_global_load_lds(
      (__attribute__((address_space(1))) void*)g,
      (__attribute__((address_space(3))) void*)l, 16, 0, 0);
}

// ---------------- all input converts in ONE kernel (region-branched, block-aligned) ------------
// items: enc 2097152 f4 | WQ 262144 | WK 262144 | WV 262144 | WO 262144 | mask 2097152 i4
__global__ __launch_bounds__(256) void cvt_all_kern(const float* __restrict__ enc,
                                                    const float* __restrict__ wq,
                                                    const float* __restrict__ wk,
                                                    const float* __restrict__ wv,
                                                    const float* __restrict__ wo_in,
                                                    const int* __restrict__ mask,
                                                    bf16* __restrict__ enc_bf,
                                                    bf16* __restrict__ wqkv,
                                                    bf16* __restrict__ wo,
                                                    unsigned char* __restrict__ mask8) {
  int i = blockIdx.x * 256 + threadIdx.x;
  if (i < 2097152) {
    float4 v = ((const float4*)enc)[i];
    bf16x4 o;
    o[0] = (bf16)v.x; o[1] = (bf16)v.y; o[2] = (bf16)v.z; o[3] = (bf16)v.w;
    ((bf16x4*)enc_bf)[i] = o;
  } else if (i < 3145728) {
    int j = i - 2097152;
    const float* src;
    bf16* dst;
    if (j < 262144) { src = wq; dst = (bf16*)wqkv; }
    else if (j < 524288) { src = wk; dst = wqkv + 1048576; j -= 262144; }
    else if (j < 786432) { src = wv; dst = wqkv + 2097152; j -= 524288; }
    else { src = wo_in; dst = wo; j -= 786432; }
    float4 v = ((const float4*)src)[j];
    bf16x4 o;
    o[0] = (bf16)v.x; o[1] = (bf16)v.y; o[2] = (bf16)v.z; o[3] = (bf16)v.w;
    ((bf16x4*)dst)[j] = o;
  } else {
    int j = i - 3145728;
    int4 v = ((const int4*)mask)[j];
    uchar4 o;
    o.x = (unsigned char)v.x; o.y = (unsigned char)v.y;
    o.z = (unsigned char)v.z; o.w = (unsigned char)v.w;
    ((uchar4*)mask8)[j] = o;
  }
}

// ---------------- 128x128 tile bf16 GEMM, C = A * Bt^T ----------------
template <bool F32OUT>
__global__ __launch_bounds__(256) void gemm_bt_kern(const bf16* __restrict__ A,
                                                    const bf16* __restrict__ Bt,
                                                    void* __restrict__ Cout,
                                                    const float* __restrict__ resid,
                                                    int K, int ldc) {
  __shared__ bf16 As[128 * 32];  // 8KB
  __shared__ bf16 Bs[128 * 32];  // 8KB
  const int lin = blockIdx.y * gridDim.x + blockIdx.x;
  const int nwg = gridDim.x * gridDim.y;
  const int chunk = nwg >> 3;
  const int v = (lin & 7) * chunk + (lin >> 3);
  const int m0 = (v / gridDim.x) * 128, n0 = (v % gridDim.x) * 128;
  const int tid = threadIdx.x;
  const int w = tid >> 6, l = tid & 63, l15 = l & 15, lg = l >> 4;
  const int wm = w >> 1, wn = w & 1;  // 2x2 waves of 64x64

  const bf16* Ab = A + (size_t)(m0 + (tid >> 2)) * K + (tid & 3) * 8;
  const bf16* Bb = Bt + (size_t)(n0 + (tid >> 2)) * K + (tid & 3) * 8;
  char* AsB = (char*)As + tid * 16;
  char* BsB = (char*)Bs + tid * 16;

  f32x4 acc[4][4] = {};
  for (int k0 = 0; k0 < K; k0 += 32) {
    gload_lds16(Ab + k0, AsB);
    gload_lds16(Ab + (size_t)64 * K + k0, AsB + 4096);
    gload_lds16(Bb + k0, BsB);
    gload_lds16(Bb + (size_t)64 * K + k0, BsB + 4096);
    __syncthreads();
    bf16x8 af[4], bfv[4];
#pragma unroll
    for (int m = 0; m < 4; m++)
      af[m] = *(const bf16x8*)&As[(wm * 64 + m * 16 + l15) * 32 + lg * 8];
#pragma unroll
    for (int n = 0; n < 4; n++)
      bfv[n] = *(const bf16x8*)&Bs[(wn * 64 + n * 16 + l15) * 32 + lg * 8];
#pragma unroll
    for (int m = 0; m < 4; m++)
#pragma unroll
      for (int n = 0; n < 4; n++) acc[m][n] = MFMA16(af[m], bfv[n], acc[m][n]);
    __syncthreads();
  }
#pragma unroll
  for (int m = 0; m < 4; m++)
#pragma unroll
    for (int n = 0; n < 4; n++)
#pragma unroll
      for (int j = 0; j < 4; j++) {
        int row = m0 + wm * 64 + m * 16 + lg * 4 + j;
        int col = n0 + wn * 64 + n * 16 + l15;
        if constexpr (F32OUT) {
          ((float*)Cout)[(size_t)row * ldc + col] =
              acc[m][n][j] + resid[(size_t)row * ldc + col];
        } else {
          ((bf16*)Cout)[(size_t)row * ldc + col] = (bf16)acc[m][n][j];
        }
      }
}

// ---------------- V transpose: qkv V-part -> vT[(b*NH+h)*DK + d][S] ----------------
__global__ __launch_bounds__(256) void vtrans_kern(const bf16* __restrict__ qkv,
                                                   bf16* __restrict__ vT) {
  int blk = blockIdx.x;
  int st = blk & 15;
  int h = (blk >> 4) & 15;
  int b = blk >> 8;
  __shared__ bf16 t[64][65];
  int tid = threadIdx.x;
  {
    int r = tid >> 2, cb = (tid & 3) * 16;
    const bf16* src = qkv + ((size_t)(b * S_ + st * 64 + r)) * 3072 + 2048 + h * DK_ + cb;
    bf16x8 u0 = *(const bf16x8*)src;
    bf16x8 u1 = *(const bf16x8*)(src + 8);
#pragma unroll
    for (int j = 0; j < 8; j++) { t[r][cb + j] = u0[j]; t[r][cb + 8 + j] = u1[j]; }
  }
  __syncthreads();
  {
    int d = tid >> 2, sb = (tid & 3) * 16;
    bf16* dst = vT + ((size_t)((b * NH_ + h) * DK_ + d)) * S_ + st * 64 + sb;
#pragma unroll
    for (int j = 0; j < 16; j++) dst[j] = t[sb + j][d];
  }
}

// ---------------- fused attention (swapped QK^T: lane owns 4 consecutive keys) ----------------
// grid 4096, 256 thr (4 waves). Wave w owns keys [w*256, w*256+256).
// D' = K*Q^T: col = query = l15 (+m*16), row = key = lg*4+j (+n*16+nb*64+w*256).
__global__ __launch_bounds__(256, 2) void attn_kern(const bf16* __restrict__ qkv,
                                                    const bf16* __restrict__ vT,
                                                    const unsigned char* __restrict__ mask8,
                                                    float* __restrict__ attn_out,
                                                    bf16* __restrict__ ctx) {
  __shared__ bf16 p_lds[32 * 1024];  // 64KB; head aliased as cross-wave reduce buf
  float(*red)[32][2] = (float(*)[32][2])p_lds;

  const int vb = (blockIdx.x & 7) * 512 + (blockIdx.x >> 3);
  const int qt = vb & 31;
  const int h = (vb >> 5) & 15;
  const int b = vb >> 9;
  const int q0 = qt * 32;
  const int tid = threadIdx.x;
  const int w = tid >> 6, l = tid & 63, l15 = l & 15, lg = l >> 4;

  // Q fragments (B operand): lane holds Q[q=l15(+m*16)][dk=kk*32+lg*8+e]
  const bf16* qbase = qkv + ((size_t)(b * S_ + q0)) * 3072 + h * DK_;
  bf16x8 aq[2][2];
#pragma unroll
  for (int m = 0; m < 2; m++)
#pragma unroll
    for (int kk = 0; kk < 2; kk++)
      aq[m][kk] = *(const bf16x8*)(qbase + (size_t)(m * 16 + l15) * 3072 + kk * 32 + lg * 8);

  // scores: sc[nb][m][n][j] = S[key = w*256+nb*64+n*16+lg*4+j][query = m*16+l15]
  f32x4 sc[4][2][4] = {};
  const bf16* kbase = qkv + ((size_t)(b * S_)) * 3072 + 1024 + h * DK_;
#pragma unroll
  for (int nb = 0; nb < 4; nb++) {
    int n0 = w * 256 + nb * 64;
#pragma unroll
    for (int n = 0; n < 4; n++)
#pragma unroll
      for (int kk = 0; kk < 2; kk++) {
        bf16x8 bk = *(const bf16x8*)(kbase + (size_t)(n0 + n * 16 + l15) * 3072 + kk * 32 + lg * 8);
#pragma unroll
        for (int m = 0; m < 2; m++) sc[nb][m][n] = MFMA16(bk, aq[m][kk], sc[nb][m][n]);
      }
  }

  // scale (log2 domain) + mask via uchar4; per-lane in-register row reduce
  const unsigned char* mbase = mask8 + (size_t)b * S_ * S_;
  const float SCL = 0.125f * 1.44269504f;  // (1/sqrt(DK)) * log2(e)
  float rmax[2] = {-3e38f, -3e38f};
#pragma unroll
  for (int m = 0; m < 2; m++) {
    int q = q0 + m * 16 + l15;
#pragma unroll
    for (int nb = 0; nb < 4; nb++)
#pragma unroll
      for (int n = 0; n < 4; n++) {
        int kb = w * 256 + nb * 64 + n * 16 + lg * 4;
        uchar4 mv = *(const uchar4*)&mbase[(size_t)q * S_ + kb];
        unsigned char mb[4] = {mv.x, mv.y, mv.z, mv.w};
#pragma unroll
        for (int j = 0; j < 4; j++) {
          float s = sc[nb][m][n][j] * SCL;
          if (mb[j] == 0) s = -1e9f;
          sc[nb][m][n][j] = s;
          rmax[m] = fmaxf(rmax[m], s);
        }
      }
  }
  // reduce across lg lane groups (lanes sharing a query differ only in bits 4,5)
#pragma unroll
  for (int m = 0; m < 2; m++) {
    float v = rmax[m];
    v = fmaxf(v, __shfl_xor(v, 16));
    v = fmaxf(v, __shfl_xor(v, 32));
    rmax[m] = v;
  }
  float rsum[2] = {0.f, 0.f};
#pragma unroll
  for (int nb = 0; nb < 4; nb++)
#pragma unroll
    for (int n = 0; n < 4; n++)
#pragma unroll
      for (int m = 0; m < 2; m++)
#pragma unroll
        for (int j = 0; j < 4; j++) {
          float e = exp2f(sc[nb][m][n][j] - rmax[m]);
          sc[nb][m][n][j] = e;
          rsum[m] += e;
        }
#pragma unroll
  for (int m = 0; m < 2; m++) {
    float v = rsum[m];
    v += __shfl_xor(v, 16);
    v += __shfl_xor(v, 32);
    rsum[m] = v;
  }
  if (lg == 0) {
#pragma unroll
    for (int m = 0; m < 2; m++) {
      red[w][m * 16 + l15][0] = rmax[m];
      red[w][m * 16 + l15][1] = rsum[m];
    }
  }
  __syncthreads();
  float scale[2];
#pragma unroll
  for (int m = 0; m < 2; m++) {
    int q = m * 16 + l15;
    float m0v = red[0][q][0], m1 = red[1][q][0], m2 = red[2][q][0], m3 = red[3][q][0];
    float gm = fmaxf(fmaxf(m0v, m1), fmaxf(m2, m3));
    float gs = red[0][q][1] * exp2f(m0v - gm) + red[1][q][1] * exp2f(m1 - gm) +
               red[2][q][1] * exp2f(m2 - gm) + red[3][q][1] * exp2f(m3 - gm);
    scale[m] = exp2f(rmax[m] - gm) / gs;
  }
  __syncthreads();  // red reads done before p_lds writes (aliased)

  // write attn f32 (nontemporal f32x4) + swizzled bf16x4 P into LDS
  float* arow = attn_out + ((size_t)(b * NH_ + h) * S_ + q0) * S_;
#pragma unroll
  for (int m = 0; m < 2; m++) {
    int q = m * 16 + l15;
#pragma unroll
    for (int nb = 0; nb < 4; nb++)
#pragma unroll
      for (int n = 0; n < 4; n++) {
        int kb = w * 256 + nb * 64 + n * 16 + lg * 4;
        f32x4 p4;
        bf16x4 pb;
#pragma unroll
        for (int j = 0; j < 4; j++) {
          float p = sc[nb][m][n][j] * scale[m];
          p4[j] = p;
          pb[j] = (bf16)p;
        }
        __builtin_nontemporal_store(p4, (f32x4*)&arow[(size_t)q * S_ + kb]);
        *(bf16x4*)&p_lds[q * 1024 + (kb ^ ((q & 7) << 3))] = pb;
      }
  }
  __syncthreads();

  // PV: wave w computes out[:, w*16 .. w*16+15]
  f32x4 o[2] = {};
  const bf16* vbase = vT + ((size_t)((b * NH_ + h) * DK_ + w * 16 + l15)) * S_;
#pragma unroll 8
  for (int ks = 0; ks < 32; ks++) {
    bf16x8 bv = *(const bf16x8*)(vbase + ks * 32 + lg * 8);
#pragma unroll
    for (int m = 0; m < 2; m++) {
      int r = m * 16 + l15;
      int e = (ks * 32 + lg * 8) ^ ((r & 7) << 3);
      bf16x8 pa = *(const bf16x8*)&p_lds[r * 1024 + e];
      o[m] = MFMA16(pa, bv, o[m]);
    }
  }
#pragma unroll
  for (int m = 0; m < 2; m++)
#pragma unroll
    for (int j = 0; j < 4; j++) {
      int r = m * 16 + lg * 4 + j;
      ctx[((size_t)(b * S_ + q0 + r)) * H_ + h * DK_ + w * 16 + l15] = (bf16)o[m][j];
    }
}

// ---------------- in-place LayerNorm over last dim (1024) ----------------
__global__ __launch_bounds__(256) void ln_kern(float* __restrict__ y,
                                               const float* __restrict__ gamma,
                                               const float* __restrict__ beta) {
  int row = blockIdx.x;
  int tid = threadIdx.x;
  float4 v = *(const float4*)&y[(size_t)row * 1024 + tid * 4];
  float s = v.x + v.y + v.z + v.w;
  float q = v.x * v.x + v.y * v.y + v.z * v.z + v.w * v.w;
#pragma unroll
  for (int m = 1; m < 64; m <<= 1) { s += __shfl_xor(s, m); q += __shfl_xor(q, m); }
  __shared__ float rb[8];
  if ((tid & 63) == 0) { rb[(tid >> 6) * 2] = s; rb[(tid >> 6) * 2 + 1] = q; }
  __syncthreads();
  s = rb[0] + rb[2] + rb[4] + rb[6];
  q = rb[1] + rb[3] + rb[5] + rb[7];
  float mu = s * (1.f / 1024.f);
  float var = q * (1.f / 1024.f) - mu * mu;
  float rstd = rsqrtf(var + 1e-6f);
  float4 g = *(const float4*)&gamma[tid * 4];
  float4 bb = *(const float4*)&beta[tid * 4];
  float4 o;
  o.x = (v.x - mu) * rstd * g.x + bb.x;
  o.y = (v.y - mu) * rstd * g.y + bb.y;
  o.z = (v.z - mu) * rstd * g.z + bb.z;
  o.w = (v.w - mu) * rstd * g.w + bb.w;
  *(float4*)&y[(size_t)row * 1024 + tid * 4] = o;
}

extern "C" void kernel_launch(void* const* d_in, const int* in_sizes, int n_in,
                              void* d_out, int out_size, void* d_ws, size_t ws_size,
                              hipStream_t stream) {
  const float* enc = (const float*)d_in[0];
  const int* mask = (const int*)d_in[1];
  const float* W_Q = (const float*)d_in[2];
  const float* W_K = (const float*)d_in[3];
  const float* W_V = (const float*)d_in[4];
  const float* W_O = (const float*)d_in[5];
  const float* ln_g = (const float*)d_in[6];
  const float* ln_b = (const float*)d_in[7];

  float* out_f32 = (float*)d_out;                          // [8192][1024]
  float* attn_f32 = (float*)d_out + (size_t)B_ * S_ * H_;  // [128][1024][1024]

  // ws layout (bytes): enc_bf 16M | wqkv 6M | wo 2M | qkv 48M | vT 16M | ctx 16M | mask8 8M
  char* wsb = (char*)d_ws;
  bf16* enc_bf = (bf16*)wsb;
  bf16* wqkv = (bf16*)(wsb + 16777216);
  bf16* wo = (bf16*)(wsb + 23068672);
  bf16* qkv = (bf16*)(wsb + 25165824);
  bf16* vT = (bf16*)(wsb + 75497472);
  bf16* ctx = (bf16*)(wsb + 92274688);
  unsigned char* mask8 = (unsigned char*)(wsb + 109051904);  // own region, no aliasing

  // 1) all converts in one launch (enc, 4 weights, mask)
  cvt_all_kern<<<20480, 256, 0, stream>>>(enc, W_Q, W_K, W_V, W_O, mask,
                                          enc_bf, wqkv, wo, mask8);

  // 2) QKV projection: [8192,1024] x [3072,1024]^T -> qkv bf16 [8192][3072]
  gemm_bt_kern<false><<<dim3(24, 64), 256, 0, stream>>>(enc_bf, wqkv, qkv, nullptr, 1024, 3072);

  // 3) V transpose -> vT
  vtrans_kern<<<2048, 256, 0, stream>>>(qkv, vT);

  // 4) fused attention (+ writes attn_dist output)
  attn_kern<<<4096, 256, 0, stream>>>(qkv, vT, mask8, attn_f32, ctx);

  // 5) output projection + residual -> d_out (pre-LN f32)
  gemm_bt_kern<true><<<dim3(8, 64), 256, 0, stream>>>(ctx, wo, out_f32, enc, 1024, 1024);

  // 6) in-place LayerNorm
  ln_kern<<<8192, 256, 0, stream>>>(out_f32, ln_g, ln_b);
}